// Round 4
// baseline (619.803 us; speedup 1.0000x reference)
//
#include <hip/hip_runtime.h>

#define NEG_SLOPE 0.2f
#define BKT_BITS 9
#define BKT_NODES 512            // 1 << BKT_BITS
#define CHUNK 8192
#define AGG_SLICES 8

__device__ __forceinline__ float lrelu(float x) { return x > 0.f ? x : NEG_SLOPE * x; }

// per-node record load: F=4 -> stride 8 {h0..h3, as, pad3}; F=2 -> stride 4 {h0,h1,as,pad}
// (scalar as sits in the same 64B line as the float4 -> 1 line per edge)
template <int F>
__device__ __forceinline__ void loadRec(const float* __restrict__ rec, int s, float4& h, float& a)
{
    if (F == 4) {
        h = *(const float4*)(rec + (size_t)s * 8);
        a = rec[(size_t)s * 8 + 4];
    } else {
        float4 r = *(const float4*)(rec + (size_t)s * 4);
        h = r; a = r.z;
    }
}

// ---------------- Layer-1 init: h1pre = x @ W1 (128x4) -> rec {h,as}, ad ----------------
__global__ void l1_init_kernel(const float* __restrict__ x,
                               const float* __restrict__ W1,
                               const float* __restrict__ a_s,
                               const float* __restrict__ a_d,
                               float* __restrict__ rec,
                               float* __restrict__ ad_,
                               int N)
{
    __shared__ float Wl[512];
    for (int i = threadIdx.x; i < 512; i += blockDim.x) Wl[i] = W1[i];
    __syncthreads();
    int n = blockIdx.x * blockDim.x + threadIdx.x;
    if (n >= N) return;
    const float4* xr = (const float4*)(x + (size_t)n * 128);
    float a0 = 0.f, a1 = 0.f, a2 = 0.f, a3 = 0.f;
#pragma unroll 8
    for (int j = 0; j < 32; ++j) {
        float4 v = xr[j];
        const float* w = &Wl[j * 16];
        a0 += v.x * w[0] + v.y * w[4] + v.z * w[8]  + v.w * w[12];
        a1 += v.x * w[1] + v.y * w[5] + v.z * w[9]  + v.w * w[13];
        a2 += v.x * w[2] + v.y * w[6] + v.z * w[10] + v.w * w[14];
        a3 += v.x * w[3] + v.y * w[7] + v.z * w[11] + v.w * w[15];
    }
    float asv = a0 * a_s[0] + a1 * a_s[1] + a2 * a_s[2] + a3 * a_s[3];
    ((float4*)rec)[2 * n]     = make_float4(a0, a1, a2, a3);
    ((float4*)rec)[2 * n + 1] = make_float4(asv, 0.f, 0.f, 0.f);
    ad_[n] = a0 * a_d[0] + a1 * a_d[1] + a2 * a_d[2] + a3 * a_d[3];
}

// ---------------- bucket histogram (dst >> BKT_BITS) ----------------
__global__ void bhist_kernel(const int* __restrict__ dst, int* __restrict__ bcnt, int E, int nbkt)
{
    __shared__ int h[256];
    h[threadIdx.x] = 0;
    __syncthreads();
    int base = blockIdx.x * CHUNK;
    int end = min(base + CHUNK, E);
    for (int i = base + threadIdx.x; i < end; i += 256)
        atomicAdd(&h[dst[i] >> BKT_BITS], 1);
    __syncthreads();
    if ((int)threadIdx.x < nbkt && h[threadIdx.x])
        atomicAdd(&bcnt[threadIdx.x], h[threadIdx.x]);
}

// ---------------- bucket offsets scan (single block; nbkt <= 256) ----------------
__global__ void bscan_kernel(const int* __restrict__ bcnt, int* __restrict__ bo,
                             int* __restrict__ gcur, int nbkt, int E)
{
    __shared__ int sh[256];
    int t = threadIdx.x;
    int v = (t < nbkt) ? bcnt[t] : 0;
    sh[t] = v;
    __syncthreads();
    for (int o = 1; o < 256; o <<= 1) {
        int u = (t >= o) ? sh[t - o] : 0;
        __syncthreads();
        sh[t] += u;
        __syncthreads();
    }
    if (t < nbkt) { int e = sh[t] - v; bo[t] = e; gcur[t] = e; }
    if (t == 0) bo[nbkt] = E;
}

// ---------------- LDS-staged bucket scatter: coalesced writes of packed edges ----------------
__global__ void __launch_bounds__(256, 1) bscat_kernel(const int* __restrict__ src,
                                                       const int* __restrict__ dst,
                                                       int* __restrict__ gcur,
                                                       int* __restrict__ packed,
                                                       int E)
{
    __shared__ int hist[256];
    __shared__ int lbase[256];
    __shared__ int gbase[256];
    __shared__ int lcur[256];
    __shared__ int sc[256];
    __shared__ int stage[CHUNK];
    __shared__ unsigned char sbkt[CHUNK];
    int t = threadIdx.x;
    hist[t] = 0; lcur[t] = 0;
    __syncthreads();
    int base = blockIdx.x * CHUNK;
    int end = min(base + CHUNK, E);
    for (int i = base + t; i < end; i += 256)
        atomicAdd(&hist[dst[i] >> BKT_BITS], 1);
    __syncthreads();
    int v = hist[t];
    sc[t] = v;
    __syncthreads();
    for (int o = 1; o < 256; o <<= 1) {
        int u = (t >= o) ? sc[t - o] : 0;
        __syncthreads();
        sc[t] += u;
        __syncthreads();
    }
    lbase[t] = sc[t] - v;
    if (v > 0) gbase[t] = atomicAdd(&gcur[t], v);   // hist[t]==0 for t>=nbkt
    __syncthreads();
    for (int i = base + t; i < end; i += 256) {
        int d = dst[i];
        int b = d >> BKT_BITS;
        int r = atomicAdd(&lcur[b], 1);
        int p = lbase[b] + r;
        stage[p] = src[i] | ((d & (BKT_NODES - 1)) << 17);
        sbkt[p] = (unsigned char)b;
    }
    __syncthreads();
    int cnt = end - base;
    for (int i = t; i < cnt; i += 256) {
        int b = sbkt[i];
        packed[gbase[b] + (i - lbase[b])] = stage[i];
    }
}

// ---------------- bucket-windowed aggregation: LDS ds_add + per-slice plane stores ----------------
// acc layout: [C][512] (SoA). planes layout: [slice][comp][NP] fully coalesced.
template <int F>
__global__ void __launch_bounds__(256) agg_kernel(const int* __restrict__ bo,
                           const int* __restrict__ packed,
                           const float* __restrict__ rec, const float* __restrict__ ad_,
                           float* __restrict__ planes, int NP, int N)
{
    constexpr int C = F + 1;
    __shared__ float acc[C * BKT_NODES];
    __shared__ float adl[BKT_NODES];
    int b  = blockIdx.x / AGG_SLICES;
    int sl = blockIdx.x % AGG_SLICES;
    int t  = threadIdx.x;
    for (int i = t; i < C * BKT_NODES; i += 256) acc[i] = 0.f;
    int nbase = b << BKT_BITS;
    for (int i = t; i < BKT_NODES; i += 256)
        adl[i] = (nbase + i < N) ? ad_[nbase + i] : 0.f;
    __syncthreads();
    int beg = bo[b], end = bo[b + 1];
    int cnt = end - beg;
    int per = (cnt + AGG_SLICES - 1) / AGG_SLICES;
    int s0 = beg + sl * per;
    int s1 = min(s0 + per, end);

    for (int i = s0 + t; i < s1; i += 1024) {
        int p0 = packed[i];
        int p1 = (i + 256 < s1) ? packed[i + 256] : -1;
        int p2 = (i + 512 < s1) ? packed[i + 512] : -1;
        int p3 = (i + 768 < s1) ? packed[i + 768] : -1;
        float4 h0, h1, h2, h3;
        float a0, a1, a2, a3;
        if (p0 >= 0) loadRec<F>(rec, p0 & 0x1FFFF, h0, a0);
        if (p1 >= 0) loadRec<F>(rec, p1 & 0x1FFFF, h1, a1);
        if (p2 >= 0) loadRec<F>(rec, p2 & 0x1FFFF, h2, a2);
        if (p3 >= 0) loadRec<F>(rec, p3 & 0x1FFFF, h3, a3);
        if (p0 >= 0) {
            int ld = p0 >> 17;
            float w = __expf(lrelu(a0 + adl[ld]));
            atomicAdd(&acc[0 * BKT_NODES + ld], w * h0.x);
            atomicAdd(&acc[1 * BKT_NODES + ld], w * h0.y);
            if (F == 4) { atomicAdd(&acc[2 * BKT_NODES + ld], w * h0.z);
                          atomicAdd(&acc[3 * BKT_NODES + ld], w * h0.w); }
            atomicAdd(&acc[F * BKT_NODES + ld], w);
        }
        if (p1 >= 0) {
            int ld = p1 >> 17;
            float w = __expf(lrelu(a1 + adl[ld]));
            atomicAdd(&acc[0 * BKT_NODES + ld], w * h1.x);
            atomicAdd(&acc[1 * BKT_NODES + ld], w * h1.y);
            if (F == 4) { atomicAdd(&acc[2 * BKT_NODES + ld], w * h1.z);
                          atomicAdd(&acc[3 * BKT_NODES + ld], w * h1.w); }
            atomicAdd(&acc[F * BKT_NODES + ld], w);
        }
        if (p2 >= 0) {
            int ld = p2 >> 17;
            float w = __expf(lrelu(a2 + adl[ld]));
            atomicAdd(&acc[0 * BKT_NODES + ld], w * h2.x);
            atomicAdd(&acc[1 * BKT_NODES + ld], w * h2.y);
            if (F == 4) { atomicAdd(&acc[2 * BKT_NODES + ld], w * h2.z);
                          atomicAdd(&acc[3 * BKT_NODES + ld], w * h2.w); }
            atomicAdd(&acc[F * BKT_NODES + ld], w);
        }
        if (p3 >= 0) {
            int ld = p3 >> 17;
            float w = __expf(lrelu(a3 + adl[ld]));
            atomicAdd(&acc[0 * BKT_NODES + ld], w * h3.x);
            atomicAdd(&acc[1 * BKT_NODES + ld], w * h3.y);
            if (F == 4) { atomicAdd(&acc[2 * BKT_NODES + ld], w * h3.z);
                          atomicAdd(&acc[3 * BKT_NODES + ld], w * h3.w); }
            atomicAdd(&acc[F * BKT_NODES + ld], w);
        }
    }
    __syncthreads();
    // coalesced plane store: plane[sl][comp][nbase + node] = acc[comp][node]
    float* pl = planes + (size_t)sl * C * NP + nbase;
    for (int i = t; i < C * BKT_NODES; i += 256)
        pl[(size_t)(i >> BKT_BITS) * NP + (i & (BKT_NODES - 1))] = acc[i];
}

// ---------------- finalize layers 1,2: sum planes + self-loop + normalize + tanh + fuse ----------------
template <int FO>
__global__ void finA_kernel(const float* __restrict__ planes, int NP,
                            const float* __restrict__ rec, const float* __restrict__ ad_,
                            const float* __restrict__ bias,
                            const float* __restrict__ Wn, const float* __restrict__ ans,
                            const float* __restrict__ andd,
                            float* __restrict__ out_h, float* __restrict__ recn,
                            float* __restrict__ adn_, int N)
{
    int n = blockIdx.x * blockDim.x + threadIdx.x;
    if (n >= N) return;
    float g[5] = {0.f, 0.f, 0.f, 0.f, 0.f};
#pragma unroll
    for (int sl = 0; sl < AGG_SLICES; ++sl) {
        const float* pl = planes + (size_t)sl * 5 * NP + n;
#pragma unroll
        for (int c = 0; c < 5; ++c) g[c] += pl[(size_t)c * NP];
    }
    float4 hv = ((const float4*)rec)[2 * n];
    float asv = rec[(size_t)n * 8 + 4];
    float w0 = __expf(lrelu(asv + ad_[n]));
    float inv = 1.f / (g[4] + w0);
    float hr[4];
    hr[0] = tanhf((g[0] + w0 * hv.x) * inv + bias[0]);
    hr[1] = tanhf((g[1] + w0 * hv.y) * inv + bias[1]);
    hr[2] = tanhf((g[2] + w0 * hv.z) * inv + bias[2]);
    hr[3] = tanhf((g[3] + w0 * hv.w) * inv + bias[3]);
    ((float4*)out_h)[n] = make_float4(hr[0], hr[1], hr[2], hr[3]);
    if (FO == 4) {
        float hp[4]; float s = 0.f, d = 0.f;
#pragma unroll
        for (int q = 0; q < 4; ++q) {
            float v = hr[0] * Wn[q] + hr[1] * Wn[4 + q] + hr[2] * Wn[8 + q] + hr[3] * Wn[12 + q];
            hp[q] = v; s += v * ans[q]; d += v * andd[q];
        }
        ((float4*)recn)[2 * n]     = make_float4(hp[0], hp[1], hp[2], hp[3]);
        ((float4*)recn)[2 * n + 1] = make_float4(s, 0.f, 0.f, 0.f);
        adn_[n] = d;
    } else {
        float hp0 = hr[0] * Wn[0] + hr[1] * Wn[2] + hr[2] * Wn[4] + hr[3] * Wn[6];
        float hp1 = hr[0] * Wn[1] + hr[1] * Wn[3] + hr[2] * Wn[5] + hr[3] * Wn[7];
        float s = hp0 * ans[0] + hp1 * ans[1];
        ((float4*)recn)[n] = make_float4(hp0, hp1, s, 0.f);
        adn_[n] = hp0 * andd[0] + hp1 * andd[1];
    }
}

// ---------------- finalize layer 3: sum planes + tanh + classifier ----------------
__global__ void finC_kernel(const float* __restrict__ planes, int NP,
                            const float* __restrict__ rec, const float* __restrict__ ad_,
                            const float* __restrict__ bias,
                            const float* __restrict__ Wc, const float* __restrict__ bc,
                            float* __restrict__ out_h, float* __restrict__ out_c, int N)
{
    int n = blockIdx.x * blockDim.x + threadIdx.x;
    if (n >= N) return;
    float g[3] = {0.f, 0.f, 0.f};
#pragma unroll
    for (int sl = 0; sl < AGG_SLICES; ++sl) {
        const float* pl = planes + (size_t)sl * 3 * NP + n;
#pragma unroll
        for (int c = 0; c < 3; ++c) g[c] += pl[(size_t)c * NP];
    }
    float4 r = ((const float4*)rec)[n];     // {h0,h1,as,pad}
    float w0 = __expf(lrelu(r.z + ad_[n]));
    float inv = 1.f / (g[2] + w0);
    float hr0 = tanhf((g[0] + w0 * r.x) * inv + bias[0]);
    float hr1 = tanhf((g[1] + w0 * r.y) * inv + bias[1]);
    ((float2*)out_h)[n] = make_float2(hr0, hr1);
    float o[8];
#pragma unroll
    for (int c = 0; c < 8; ++c) o[c] = hr0 * Wc[c] + hr1 * Wc[8 + c] + bc[c];
    float4* op = (float4*)(out_c + (size_t)n * 8);
    op[0] = make_float4(o[0], o[1], o[2], o[3]);
    op[1] = make_float4(o[4], o[5], o[6], o[7]);
}

extern "C" void kernel_launch(void* const* d_in, const int* in_sizes, int n_in,
                              void* d_out, int out_size, void* d_ws, size_t ws_size,
                              hipStream_t stream)
{
    const float* x   = (const float*)d_in[0];
    const int*   ei  = (const int*)d_in[1];
    const float* W1  = (const float*)d_in[2];
    const float* a1s = (const float*)d_in[3];
    const float* a1d = (const float*)d_in[4];
    const float* b1  = (const float*)d_in[5];
    const float* W2  = (const float*)d_in[6];
    const float* a2s = (const float*)d_in[7];
    const float* a2d = (const float*)d_in[8];
    const float* b2  = (const float*)d_in[9];
    const float* W3  = (const float*)d_in[10];
    const float* a3s = (const float*)d_in[11];
    const float* a3d = (const float*)d_in[12];
    const float* b3  = (const float*)d_in[13];
    const float* Wc  = (const float*)d_in[14];
    const float* bc  = (const float*)d_in[15];

    const int N = in_sizes[0] / 128;
    const int E = in_sizes[1] / 2;
    const int* src = ei;
    const int* dst = ei + E;
    const int nbkt = (N + BKT_NODES - 1) >> BKT_BITS;      // 196 for N=100k (<=256)
    const int NP = nbkt * BKT_NODES;                       // padded node count
    const int nchunks = (E + CHUNK - 1) / CHUNK;

    float* out    = (float*)d_out;
    float* out_h1 = out;
    float* out_h2 = out + (size_t)4 * N;
    float* out_h3 = out + (size_t)8 * N;
    float* out_c  = out + (size_t)10 * N;

    char* ws = (char*)d_ws;
    size_t off = 0;
    auto alloc = [&](size_t bytes) -> void* {
        void* p = ws + off;
        off = (off + bytes + 255) & ~(size_t)255;
        return p;
    };
    int*   bcnt   = (int*)  alloc(256 * 4);
    int*   bo     = (int*)  alloc(257 * 4);
    int*   gcur   = (int*)  alloc(256 * 4);
    int*   packed = (int*)  alloc((size_t)E * 4);
    float* recA   = (float*)alloc((size_t)N * 8 * 4);
    float* adA    = (float*)alloc((size_t)N * 4);
    float* recB   = (float*)alloc((size_t)N * 8 * 4);
    float* adB    = (float*)alloc((size_t)N * 4);
    float* planes = (float*)alloc((size_t)AGG_SLICES * NP * 5 * 4);
    if (off > ws_size) return;  // workspace too small — bail visibly

    const int nb = (N + 255) / 256;

    hipMemsetAsync(bcnt, 0, 256 * 4, stream);
    l1_init_kernel<<<nb, 256, 0, stream>>>(x, W1, a1s, a1d, recA, adA, N);
    bhist_kernel<<<nchunks, 256, 0, stream>>>(dst, bcnt, E, nbkt);
    bscan_kernel<<<1, 256, 0, stream>>>(bcnt, bo, gcur, nbkt, E);
    bscat_kernel<<<nchunks, 256, 0, stream>>>(src, dst, gcur, packed, E);

    // layer 1
    agg_kernel<4><<<nbkt * AGG_SLICES, 256, 0, stream>>>(bo, packed, recA, adA, planes, NP, N);
    finA_kernel<4><<<nb, 256, 0, stream>>>(planes, NP, recA, adA, b1, W2, a2s, a2d,
                                           out_h1, recB, adB, N);
    // layer 2 (recA reused as layer-3 input records, stride 4)
    agg_kernel<4><<<nbkt * AGG_SLICES, 256, 0, stream>>>(bo, packed, recB, adB, planes, NP, N);
    finA_kernel<2><<<nb, 256, 0, stream>>>(planes, NP, recB, adB, b2, W3, a3s, a3d,
                                           out_h2, recA, adA, N);
    // layer 3
    agg_kernel<2><<<nbkt * AGG_SLICES, 256, 0, stream>>>(bo, packed, recA, adA, planes, NP, N);
    finC_kernel<<<nb, 256, 0, stream>>>(planes, NP, recA, adA, b3, Wc, bc, out_h3, out_c, N);
}

// Round 5
// 611.860 us; speedup vs baseline: 1.0130x; 1.0130x over previous
//
#include <hip/hip_runtime.h>
#include <hip/hip_fp16.h>

#define NEG_SLOPE 0.2f
#define BKT_BITS 9
#define BKT_NODES 512            // 1 << BKT_BITS
#define CHUNK 8192
#define AGG_SLICES 8

__device__ __forceinline__ float lrelu(float x) { return x > 0.f ? x : NEG_SLOPE * x; }

// Real hardware LDS float atomic add (HIP's atomicAdd(float*) on LDS lowers to a CAS
// loop without -munsafe-fp-atomics; this emits ds_add_f32 directly).
// LDS flat addresses have the byte offset in the low 32 bits.
__device__ __forceinline__ void ldsAddF32(float* p, float v) {
    asm volatile("ds_add_f32 %0, %1" : : "v"((unsigned)(uintptr_t)p), "v"(v));
}

union H2F { __half2 h; float f; };

__device__ __forceinline__ float2 unpackH2(float bits) {
    H2F u; u.f = bits; return __half22float2(u.h);
}
__device__ __forceinline__ float packH2(float a, float b) {
    H2F u; u.h = __float22half2_rn(make_float2(a, b)); return u.f;
}

// per-node record: 16B both layer types.
// F=4: {h01 f16x2, h23 f16x2, asv f32, pad}   F=2: {h0 f32, h1 f32, asv f32, pad}
template <int F>
__device__ __forceinline__ void loadRec(const float* __restrict__ rec, int s, float4& h, float& a)
{
    float4 r = ((const float4*)rec)[s];
    if (F == 4) {
        float2 h01 = unpackH2(r.x);
        float2 h23 = unpackH2(r.y);
        h = make_float4(h01.x, h01.y, h23.x, h23.y);
        a = r.z;
    } else {
        h = r; a = r.z;
    }
}

// ---------------- Layer-1 init: h1pre = x @ W1 (128x4) -> rec {f16 h, asv}, ad ----------------
__global__ void l1_init_kernel(const float* __restrict__ x,
                               const float* __restrict__ W1,
                               const float* __restrict__ a_s,
                               const float* __restrict__ a_d,
                               float* __restrict__ rec,
                               float* __restrict__ ad_,
                               int N)
{
    __shared__ float Wl[512];
    for (int i = threadIdx.x; i < 512; i += blockDim.x) Wl[i] = W1[i];
    __syncthreads();
    int n = blockIdx.x * blockDim.x + threadIdx.x;
    if (n >= N) return;
    const float4* xr = (const float4*)(x + (size_t)n * 128);
    float a0 = 0.f, a1 = 0.f, a2 = 0.f, a3 = 0.f;
#pragma unroll 8
    for (int j = 0; j < 32; ++j) {
        float4 v = xr[j];
        const float* w = &Wl[j * 16];
        a0 += v.x * w[0] + v.y * w[4] + v.z * w[8]  + v.w * w[12];
        a1 += v.x * w[1] + v.y * w[5] + v.z * w[9]  + v.w * w[13];
        a2 += v.x * w[2] + v.y * w[6] + v.z * w[10] + v.w * w[14];
        a3 += v.x * w[3] + v.y * w[7] + v.z * w[11] + v.w * w[15];
    }
    float asv = a0 * a_s[0] + a1 * a_s[1] + a2 * a_s[2] + a3 * a_s[3];
    ((float4*)rec)[n] = make_float4(packH2(a0, a1), packH2(a2, a3), asv, 0.f);
    ad_[n] = a0 * a_d[0] + a1 * a_d[1] + a2 * a_d[2] + a3 * a_d[3];
}

// ---------------- bucket histogram (dst >> BKT_BITS) ----------------
__global__ void bhist_kernel(const int* __restrict__ dst, int* __restrict__ bcnt, int E, int nbkt)
{
    __shared__ int h[256];
    h[threadIdx.x] = 0;
    __syncthreads();
    int base = blockIdx.x * CHUNK;
    int end = min(base + CHUNK, E);
    for (int i = base + threadIdx.x; i < end; i += 256)
        atomicAdd(&h[dst[i] >> BKT_BITS], 1);
    __syncthreads();
    if ((int)threadIdx.x < nbkt && h[threadIdx.x])
        atomicAdd(&bcnt[threadIdx.x], h[threadIdx.x]);
}

// ---------------- bucket offsets scan (single block; nbkt <= 256) ----------------
__global__ void bscan_kernel(const int* __restrict__ bcnt, int* __restrict__ bo,
                             int* __restrict__ gcur, int nbkt, int E)
{
    __shared__ int sh[256];
    int t = threadIdx.x;
    int v = (t < nbkt) ? bcnt[t] : 0;
    sh[t] = v;
    __syncthreads();
    for (int o = 1; o < 256; o <<= 1) {
        int u = (t >= o) ? sh[t - o] : 0;
        __syncthreads();
        sh[t] += u;
        __syncthreads();
    }
    if (t < nbkt) { int e = sh[t] - v; bo[t] = e; gcur[t] = e; }
    if (t == 0) bo[nbkt] = E;
}

// ---------------- LDS-staged bucket scatter: coalesced writes of packed edges ----------------
__global__ void __launch_bounds__(256, 1) bscat_kernel(const int* __restrict__ src,
                                                       const int* __restrict__ dst,
                                                       int* __restrict__ gcur,
                                                       int* __restrict__ packed,
                                                       int E)
{
    __shared__ int hist[256];
    __shared__ int lbase[256];
    __shared__ int gbase[256];
    __shared__ int lcur[256];
    __shared__ int sc[256];
    __shared__ int stage[CHUNK];
    __shared__ unsigned char sbkt[CHUNK];
    int t = threadIdx.x;
    hist[t] = 0; lcur[t] = 0;
    __syncthreads();
    int base = blockIdx.x * CHUNK;
    int end = min(base + CHUNK, E);
    for (int i = base + t; i < end; i += 256)
        atomicAdd(&hist[dst[i] >> BKT_BITS], 1);
    __syncthreads();
    int v = hist[t];
    sc[t] = v;
    __syncthreads();
    for (int o = 1; o < 256; o <<= 1) {
        int u = (t >= o) ? sc[t - o] : 0;
        __syncthreads();
        sc[t] += u;
        __syncthreads();
    }
    lbase[t] = sc[t] - v;
    if (v > 0) gbase[t] = atomicAdd(&gcur[t], v);   // hist[t]==0 for t>=nbkt
    __syncthreads();
    for (int i = base + t; i < end; i += 256) {
        int d = dst[i];
        int b = d >> BKT_BITS;
        int r = atomicAdd(&lcur[b], 1);
        int p = lbase[b] + r;
        stage[p] = src[i] | ((d & (BKT_NODES - 1)) << 17);
        sbkt[p] = (unsigned char)b;
    }
    __syncthreads();
    int cnt = end - base;
    for (int i = t; i < cnt; i += 256) {
        int b = sbkt[i];
        packed[gbase[b] + (i - lbase[b])] = stage[i];
    }
}

// ---------------- per-edge consume: real ds_add_f32 into SoA acc[C][512] ----------------
template <int F>
__device__ __forceinline__ void consume(float* __restrict__ acc, const float* __restrict__ adl,
                                        int p, const float4& h, float a)
{
    int ld = p >> 17;
    float w = __expf(lrelu(a + adl[ld]));
    ldsAddF32(&acc[0 * BKT_NODES + ld], w * h.x);
    ldsAddF32(&acc[1 * BKT_NODES + ld], w * h.y);
    if (F == 4) {
        ldsAddF32(&acc[2 * BKT_NODES + ld], w * h.z);
        ldsAddF32(&acc[3 * BKT_NODES + ld], w * h.w);
    }
    ldsAddF32(&acc[F * BKT_NODES + ld], w);
}

// ---------------- bucket-windowed aggregation: ds_add_f32 + per-slice plane stores ----------------
template <int F>
__global__ void __launch_bounds__(256) agg_kernel(const int* __restrict__ bo,
                           const int* __restrict__ packed,
                           const float* __restrict__ rec, const float* __restrict__ ad_,
                           float* __restrict__ planes, int NP, int N)
{
    constexpr int C = F + 1;
    __shared__ float acc[C * BKT_NODES];
    __shared__ float adl[BKT_NODES];
    int b  = blockIdx.x / AGG_SLICES;
    int sl = blockIdx.x % AGG_SLICES;
    int t  = threadIdx.x;
    for (int i = t; i < C * BKT_NODES; i += 256) acc[i] = 0.f;
    int nbase = b << BKT_BITS;
    for (int i = t; i < BKT_NODES; i += 256)
        adl[i] = (nbase + i < N) ? ad_[nbase + i] : 0.f;
    __syncthreads();
    int beg = bo[b], end = bo[b + 1];
    int cnt = end - beg;
    int per = (cnt + AGG_SLICES - 1) / AGG_SLICES;
    int s0 = beg + sl * per;
    int s1 = min(s0 + per, end);
    int len = s1 - s0;
    if (len > 0) {
        const int* pk = packed + s0;
        int nfull = len >> 10;          // iterations where all 4×256 lanes are valid
        for (int k = 0; k < nfull; ++k) {
            int i = (k << 10) + t;
            // 4 independent coalesced stream loads + 4 independent gathers in flight
            int p0 = pk[i];
            int p1 = pk[i + 256];
            int p2 = pk[i + 512];
            int p3 = pk[i + 768];
            float4 h0, h1, h2, h3;
            float a0, a1, a2, a3;
            loadRec<F>(rec, p0 & 0x1FFFF, h0, a0);
            loadRec<F>(rec, p1 & 0x1FFFF, h1, a1);
            loadRec<F>(rec, p2 & 0x1FFFF, h2, a2);
            loadRec<F>(rec, p3 & 0x1FFFF, h3, a3);
            consume<F>(acc, adl, p0, h0, a0);
            consume<F>(acc, adl, p1, h1, a1);
            consume<F>(acc, adl, p2, h2, a2);
            consume<F>(acc, adl, p3, h3, a3);
        }
        for (int i = (nfull << 10) + t; i < len; i += 256) {
            int p0 = pk[i];
            float4 h0; float a0;
            loadRec<F>(rec, p0 & 0x1FFFF, h0, a0);
            consume<F>(acc, adl, p0, h0, a0);
        }
    }
    // drain our asm ds ops before the barrier, then coalesced plane store
    asm volatile("s_waitcnt lgkmcnt(0)" ::: "memory");
    __syncthreads();
    float* pl = planes + (size_t)sl * C * NP + nbase;
    for (int i = t; i < C * BKT_NODES; i += 256)
        pl[(size_t)(i >> BKT_BITS) * NP + (i & (BKT_NODES - 1))] = acc[i];
}

// ---------------- finalize layers 1,2: sum planes + self-loop + normalize + tanh + fuse ----------------
template <int FO>
__global__ void finA_kernel(const float* __restrict__ planes, int NP,
                            const float* __restrict__ rec, const float* __restrict__ ad_,
                            const float* __restrict__ bias,
                            const float* __restrict__ Wn, const float* __restrict__ ans,
                            const float* __restrict__ andd,
                            float* __restrict__ out_h, float* __restrict__ recn,
                            float* __restrict__ adn_, int N)
{
    int n = blockIdx.x * blockDim.x + threadIdx.x;
    if (n >= N) return;
    float g[5] = {0.f, 0.f, 0.f, 0.f, 0.f};
#pragma unroll
    for (int sl = 0; sl < AGG_SLICES; ++sl) {
        const float* pl = planes + (size_t)sl * 5 * NP + n;
#pragma unroll
        for (int c = 0; c < 5; ++c) g[c] += pl[(size_t)c * NP];
    }
    float4 r = ((const float4*)rec)[n];
    float2 h01 = unpackH2(r.x);
    float2 h23 = unpackH2(r.y);
    float w0 = __expf(lrelu(r.z + ad_[n]));
    float inv = 1.f / (g[4] + w0);
    float hr[4];
    hr[0] = tanhf((g[0] + w0 * h01.x) * inv + bias[0]);
    hr[1] = tanhf((g[1] + w0 * h01.y) * inv + bias[1]);
    hr[2] = tanhf((g[2] + w0 * h23.x) * inv + bias[2]);
    hr[3] = tanhf((g[3] + w0 * h23.y) * inv + bias[3]);
    ((float4*)out_h)[n] = make_float4(hr[0], hr[1], hr[2], hr[3]);
    if (FO == 4) {
        float hp[4]; float s = 0.f, d = 0.f;
#pragma unroll
        for (int q = 0; q < 4; ++q) {
            float v = hr[0] * Wn[q] + hr[1] * Wn[4 + q] + hr[2] * Wn[8 + q] + hr[3] * Wn[12 + q];
            hp[q] = v; s += v * ans[q]; d += v * andd[q];
        }
        ((float4*)recn)[n] = make_float4(packH2(hp[0], hp[1]), packH2(hp[2], hp[3]), s, 0.f);
        adn_[n] = d;
    } else {
        float hp0 = hr[0] * Wn[0] + hr[1] * Wn[2] + hr[2] * Wn[4] + hr[3] * Wn[6];
        float hp1 = hr[0] * Wn[1] + hr[1] * Wn[3] + hr[2] * Wn[5] + hr[3] * Wn[7];
        float s = hp0 * ans[0] + hp1 * ans[1];
        ((float4*)recn)[n] = make_float4(hp0, hp1, s, 0.f);
        adn_[n] = hp0 * andd[0] + hp1 * andd[1];
    }
}

// ---------------- finalize layer 3: sum planes + tanh + classifier ----------------
__global__ void finC_kernel(const float* __restrict__ planes, int NP,
                            const float* __restrict__ rec, const float* __restrict__ ad_,
                            const float* __restrict__ bias,
                            const float* __restrict__ Wc, const float* __restrict__ bc,
                            float* __restrict__ out_h, float* __restrict__ out_c, int N)
{
    int n = blockIdx.x * blockDim.x + threadIdx.x;
    if (n >= N) return;
    float g[3] = {0.f, 0.f, 0.f};
#pragma unroll
    for (int sl = 0; sl < AGG_SLICES; ++sl) {
        const float* pl = planes + (size_t)sl * 3 * NP + n;
#pragma unroll
        for (int c = 0; c < 3; ++c) g[c] += pl[(size_t)c * NP];
    }
    float4 r = ((const float4*)rec)[n];     // {h0,h1,as,pad} f32
    float w0 = __expf(lrelu(r.z + ad_[n]));
    float inv = 1.f / (g[2] + w0);
    float hr0 = tanhf((g[0] + w0 * r.x) * inv + bias[0]);
    float hr1 = tanhf((g[1] + w0 * r.y) * inv + bias[1]);
    ((float2*)out_h)[n] = make_float2(hr0, hr1);
    float o[8];
#pragma unroll
    for (int c = 0; c < 8; ++c) o[c] = hr0 * Wc[c] + hr1 * Wc[8 + c] + bc[c];
    float4* op = (float4*)(out_c + (size_t)n * 8);
    op[0] = make_float4(o[0], o[1], o[2], o[3]);
    op[1] = make_float4(o[4], o[5], o[6], o[7]);
}

extern "C" void kernel_launch(void* const* d_in, const int* in_sizes, int n_in,
                              void* d_out, int out_size, void* d_ws, size_t ws_size,
                              hipStream_t stream)
{
    const float* x   = (const float*)d_in[0];
    const int*   ei  = (const int*)d_in[1];
    const float* W1  = (const float*)d_in[2];
    const float* a1s = (const float*)d_in[3];
    const float* a1d = (const float*)d_in[4];
    const float* b1  = (const float*)d_in[5];
    const float* W2  = (const float*)d_in[6];
    const float* a2s = (const float*)d_in[7];
    const float* a2d = (const float*)d_in[8];
    const float* b2  = (const float*)d_in[9];
    const float* W3  = (const float*)d_in[10];
    const float* a3s = (const float*)d_in[11];
    const float* a3d = (const float*)d_in[12];
    const float* b3  = (const float*)d_in[13];
    const float* Wc  = (const float*)d_in[14];
    const float* bc  = (const float*)d_in[15];

    const int N = in_sizes[0] / 128;
    const int E = in_sizes[1] / 2;
    const int* src = ei;
    const int* dst = ei + E;
    const int nbkt = (N + BKT_NODES - 1) >> BKT_BITS;      // 196 for N=100k (<=256)
    const int NP = nbkt * BKT_NODES;                       // padded node count
    const int nchunks = (E + CHUNK - 1) / CHUNK;

    float* out    = (float*)d_out;
    float* out_h1 = out;
    float* out_h2 = out + (size_t)4 * N;
    float* out_h3 = out + (size_t)8 * N;
    float* out_c  = out + (size_t)10 * N;

    char* ws = (char*)d_ws;
    size_t off = 0;
    auto alloc = [&](size_t bytes) -> void* {
        void* p = ws + off;
        off = (off + bytes + 255) & ~(size_t)255;
        return p;
    };
    int*   bcnt   = (int*)  alloc(256 * 4);
    int*   bo     = (int*)  alloc(257 * 4);
    int*   gcur   = (int*)  alloc(256 * 4);
    int*   packed = (int*)  alloc((size_t)E * 4);
    float* recA   = (float*)alloc((size_t)N * 4 * 4);
    float* adA    = (float*)alloc((size_t)N * 4);
    float* recB   = (float*)alloc((size_t)N * 4 * 4);
    float* adB    = (float*)alloc((size_t)N * 4);
    float* planes = (float*)alloc((size_t)AGG_SLICES * NP * 5 * 4);
    if (off > ws_size) return;  // workspace too small — bail visibly

    const int nb = (N + 255) / 256;

    hipMemsetAsync(bcnt, 0, 256 * 4, stream);
    l1_init_kernel<<<nb, 256, 0, stream>>>(x, W1, a1s, a1d, recA, adA, N);
    bhist_kernel<<<nchunks, 256, 0, stream>>>(dst, bcnt, E, nbkt);
    bscan_kernel<<<1, 256, 0, stream>>>(bcnt, bo, gcur, nbkt, E);
    bscat_kernel<<<nchunks, 256, 0, stream>>>(src, dst, gcur, packed, E);

    // layer 1
    agg_kernel<4><<<nbkt * AGG_SLICES, 256, 0, stream>>>(bo, packed, recA, adA, planes, NP, N);
    finA_kernel<4><<<nb, 256, 0, stream>>>(planes, NP, recA, adA, b1, W2, a2s, a2d,
                                           out_h1, recB, adB, N);
    // layer 2
    agg_kernel<4><<<nbkt * AGG_SLICES, 256, 0, stream>>>(bo, packed, recB, adB, planes, NP, N);
    finA_kernel<2><<<nb, 256, 0, stream>>>(planes, NP, recB, adB, b2, W3, a3s, a3d,
                                           out_h2, recA, adA, N);
    // layer 3 (recA now holds f32 {h0,h1,as,pad})
    agg_kernel<2><<<nbkt * AGG_SLICES, 256, 0, stream>>>(bo, packed, recA, adA, planes, NP, N);
    finC_kernel<<<nb, 256, 0, stream>>>(planes, NP, recA, adA, b3, Wc, bc, out_h3, out_c, N);
}